// Round 7
// baseline (1187.832 us; speedup 1.0000x reference)
//
#include <hip/hip_runtime.h>
#include <hip/hip_bf16.h>
#include <math.h>

#define NH   12
#define HD   64
#define HDIM 768
#define SEQ  257
#define MIDP 128
#define BTOT 2048
#define CS   32
#define NCH  9      // ceil(257/32)

typedef __attribute__((ext_vector_type(8))) short short8;
typedef __attribute__((ext_vector_type(4))) float f32x4;

__device__ inline unsigned cvt2(float lo, float hi){
  union { __hip_bfloat162 h; unsigned u; } z;
  z.h = __float22bfloat162_rn(make_float2(lo, hi));   // lo -> low 16 bits
  return z.u;
}
__device__ inline float bf_as_f(unsigned short h){
  union { unsigned u; float f; } v; v.u = ((unsigned)h) << 16; return v.f;
}
__device__ inline float dot4(float4 a, float4 b){
  return fmaf(a.x,b.x, fmaf(a.y,b.y, fmaf(a.z,b.z, a.w*b.w)));
}
// LDS-only barrier: drain LDS ops, leave global loads in flight (no vmcnt drain)
__device__ inline void barrier_lds(){
  __builtin_amdgcn_sched_barrier(0);
  asm volatile("s_waitcnt lgkmcnt(0)" ::: "memory");
  __builtin_amdgcn_s_barrier();
  __builtin_amdgcn_sched_barrier(0);
}

// ---------------- K0: moments + pe rank-3 decomposition tables ----------------
// pe[s,j] = alpha_s*A_j + beta_s*B_j + C_j ; alpha=pos*rstd, beta=rstd
__global__ __launch_bounds__(256) void k0_pre(
    const float* __restrict__ pe_w, const float* __restrict__ pe_b,
    const float* __restrict__ ln_g, const float* __restrict__ ln_b,
    const float* __restrict__ pos_bias,
    float* __restrict__ pemid, float* __restrict__ alpha, float* __restrict__ beta,
    float* __restrict__ Av, float* __restrict__ Bv, float* __restrict__ Cv,
    float* __restrict__ pbT) {
  __shared__ float red[5][256];
  const int t = threadIdx.x;
  float sw=0.f, sb=0.f, sww=0.f, swb=0.f, sbb=0.f;
  for (int j=t; j<HDIM; j+=256) {
    float w=pe_w[j], b=pe_b[j];
    sw+=w; sb+=b; sww+=w*w; swb+=w*b; sbb+=b*b;
  }
  red[0][t]=sw; red[1][t]=sb; red[2][t]=sww; red[3][t]=swb; red[4][t]=sbb;
  __syncthreads();
  for (int off=128; off>0; off>>=1) {
    if (t<off) {
      red[0][t]+=red[0][t+off]; red[1][t]+=red[1][t+off]; red[2][t]+=red[2][t+off];
      red[3][t]+=red[3][t+off]; red[4][t]+=red[4][t+off];
    }
    __syncthreads();
  }
  const float inv = 1.0f/(float)HDIM;
  const float mw=red[0][0]*inv, mc=red[1][0]*inv;
  const float Vw =red[2][0]*inv - mw*mw;
  const float Cwc=red[3][0]*inv - mw*mc;
  const float Vc =red[4][0]*inv - mc*mc;
  for (int s=t; s<288; s+=256) {
    if (s < SEQ) {
      float pos = (float)(s - MIDP) / ((float)MIDP + 1e-6f);
      float var = pos*pos*Vw + 2.f*pos*Cwc + Vc;
      float rstd = rsqrtf(var + 1e-5f);
      alpha[s] = pos*rstd; beta[s] = rstd;
    } else { alpha[s] = 0.f; beta[s] = 0.f; }
  }
  const float rstd0 = rsqrtf(Vc + 1e-5f);
  for (int j=t; j<HDIM; j+=256) {
    float g = ln_g[j];
    Av[j] = (pe_w[j]-mw)*g;
    Bv[j] = (pe_b[j]-mc)*g;
    Cv[j] = ln_b[j];
    pemid[j] = (pe_b[j]-mc)*rstd0*g + ln_b[j];
  }
  for (int i=t; i<288*16; i+=256) {
    int s = i>>4, h = i&15;
    pbT[i] = (s<SEQ && h<NH) ? pos_bias[h*SEQ+s] : 0.f;
  }
}

// ---------------- tiled fp32 GEMM with epilogue scale ----------------
__global__ __launch_bounds__(256) void gemm64(
    const float* __restrict__ A, long lda, long aoffz,
    const float* __restrict__ Bm, long ldb, long boffz, int bT,
    float* __restrict__ C, long ldc, long coffz,
    int K,
    const float* __restrict__ bias, long biasoffz,
    const float* __restrict__ avec, float scale) {
  __shared__ __align__(16) float As[16][68];
  __shared__ __align__(16) float Bs[16][68];
  const int tid = threadIdx.x;
  const int tx = tid & 15, ty = tid >> 4;
  const int z = blockIdx.z;
  const long n0 = (long)blockIdx.y * 64;
  A  += (long)blockIdx.x*64*lda + (long)z*aoffz;
  Bm += (long)z*boffz;
  C  += (long)blockIdx.x*64*ldc + n0 + (long)z*coffz;
  float acc[4][4] = {};
  const int lm = tid & 63;
  const int lk = tid >> 6;

  for (int k0 = 0; k0 < K; k0 += 16) {
    float4 a = *(const float4*)&A[(long)lm*lda + k0 + lk*4];
    if (avec) {
      float4 av = *(const float4*)&avec[k0 + lk*4];
      a.x += av.x; a.y += av.y; a.z += av.z; a.w += av.w;
    }
    As[lk*4+0][lm]=a.x; As[lk*4+1][lm]=a.y; As[lk*4+2][lm]=a.z; As[lk*4+3][lm]=a.w;
    if (bT) {
      float4 b = *(const float4*)&Bm[(n0+lm)*ldb + k0 + lk*4];
      Bs[lk*4+0][lm]=b.x; Bs[lk*4+1][lm]=b.y; Bs[lk*4+2][lm]=b.z; Bs[lk*4+3][lm]=b.w;
    } else {
      #pragma unroll
      for (int i=0;i<4;i++)
        Bs[lk*4+i][lm] = Bm[(long)(k0+lk*4+i)*ldb + n0 + lm];
    }
    __syncthreads();
    #pragma unroll
    for (int k=0;k<16;k++) {
      float4 a4 = *(const float4*)&As[k][ty*4];
      float4 b4 = *(const float4*)&Bs[k][tx*4];
      float aa[4] = {a4.x,a4.y,a4.z,a4.w};
      float bb[4] = {b4.x,b4.y,b4.z,b4.w};
      #pragma unroll
      for (int i=0;i<4;i++)
        #pragma unroll
        for (int j=0;j<4;j++)
          acc[i][j] = fmaf(aa[i], bb[j], acc[i][j]);
    }
    __syncthreads();
  }
  float4 bs = make_float4(0.f,0.f,0.f,0.f);
  if (bias) bs = *(const float4*)&bias[(long)z*biasoffz + n0 + tx*4];
  #pragma unroll
  for (int i=0;i<4;i++) {
    float4 o;
    o.x = (acc[i][0]+bs.x)*scale; o.y = (acc[i][1]+bs.y)*scale;
    o.z = (acc[i][2]+bs.z)*scale; o.w = (acc[i][3]+bs.w)*scale;
    *(float4*)&C[(long)(ty*4+i)*ldc + tx*4] = o;
  }
}

// ---------------- kp: per-(b,h) scalars ca=u'.A, cb=u'.B, cc=u'.C + q'.bk ----------------
__global__ __launch_bounds__(256) void kp(
    const float* __restrict__ q, const float* __restrict__ u, const float* __restrict__ bk,
    const float* __restrict__ Av, const float* __restrict__ Bv, const float* __restrict__ Cv,
    float* __restrict__ ca, float* __restrict__ cb, float* __restrict__ cc, int nb) {
  const int wid = blockIdx.x*4 + (threadIdx.x >> 6);
  const int lane = threadIdx.x & 63;
  if (wid >= nb*NH) return;
  const int b = wid / NH, h = wid % NH;
  const float* up = u + (long)b*(NH*HDIM) + h*HDIM;
  float pa=0.f, pb_=0.f, pc=0.f;
  #pragma unroll
  for (int e=0;e<3;e++) {
    int c4 = (lane + 64*e)*4;
    float4 uu = *(const float4*)&up[c4];
    pa += dot4(uu, *(const float4*)&Av[c4]);
    pb_+= dot4(uu, *(const float4*)&Bv[c4]);
    pc += dot4(uu, *(const float4*)&Cv[c4]);
  }
  if (lane < 16) {
    float4 qq = *(const float4*)&q[(long)b*HDIM + h*HD + lane*4];
    float4 bb = *(const float4*)&bk[h*HD + lane*4];
    pc += dot4(qq, bb);
  }
  #pragma unroll
  for (int mlog=0; mlog<6; mlog++) {
    int msk = 1<<mlog;
    pa += __shfl_xor(pa, msk);
    pb_+= __shfl_xor(pb_, msk);
    pc += __shfl_xor(pc, msk);
  }
  if (lane == 0) { ca[wid]=pa; cb[wid]=pb_; cc[wid]=pc; }
}

// ---------------- K3 v6: swapped-MFMA scores (S^T), CS=32, LDS-only barriers ----------------
// Block per batch. 32-row chunks of raw hs as XOR-swizzled bf16 rows in LDS.
// Score: wave w owns s-rows w*8..w*8+7; full K=768 per wave (24 mfma, A=u' from LDS,
//        B=x rows); D col=s (lane&15), row=h ((lane>>4)*4+r) -> exp per-lane, no sred.
// PV: VALU, all 256 threads, m[12][3] regs, w from f32 wl[32][16] broadcast reads.
// 3 LDS-only barriers per chunk; global prefetch (24 float4/thread) stays in flight
// across barriers (vmcnt not drained).
__global__ __launch_bounds__(256, 2) void k3_mfma(
    const float* __restrict__ hs, int b0,
    const float* __restrict__ u,
    const float* __restrict__ ca, const float* __restrict__ cb, const float* __restrict__ cc,
    const float* __restrict__ alpha, const float* __restrict__ beta,
    const float* __restrict__ Av, const float* __restrict__ Bv, const float* __restrict__ Cv,
    const float* __restrict__ pbT, float* __restrict__ mout) {
  const int t   = threadIdx.x;
  const int l   = t & 63;
  const int w   = t >> 6;
  const int l15 = l & 15;
  const int lg  = l >> 4;
  const int bb  = blockIdx.x;
  const int b   = b0 + bb;

  __shared__ __align__(16) unsigned short xbf[CS*768];   // 49152 B
  __shared__ __align__(16) unsigned short uld[12*776];   // 18624 B (pad 776 vs 768)
  __shared__ __align__(16) float wl[CS][16];             //  2048 B
  __shared__ float al_s[288], be_s[288];                 //  2304 B
  __shared__ float hsum[3][4][16];                       //   768 B

  for (int i=t; i<288; i+=256) { al_s[i]=alpha[i]; be_s[i]=beta[i]; }

  // stage u' (f32 global) -> bf16 LDS [12][776]
  const float* ub = u + (long)bb*(NH*HDIM);
  #pragma unroll
  for (int e=0; e<9; ++e) {
    int idx4 = t + 256*e;                 // 0..2303 float4s
    int h  = idx4 / 192;
    int c4 = idx4 % 192;
    float4 v = *(const float4*)&ub[h*HDIM + c4*4];
    uint2 p; p.x = cvt2(v.x, v.y); p.y = cvt2(v.z, v.w);
    *(uint2*)&uld[h*776 + c4*4] = p;
  }

  // per-lane head params for h = lg*4+r
  float ca4[4], cb4[4], cc4[4];
  #pragma unroll
  for (int r=0;r<4;++r) {
    int h = lg*4 + r;
    bool vv = (h < NH);
    ca4[r] = vv ? ca[bb*NH+h] : 0.f;
    cb4[r] = vv ? cb[bb*NH+h] : 0.f;
    cc4[r] = vv ? cc[bb*NH+h] : 0.f;
  }

  float m[NH][3];
  #pragma unroll
  for (int h=0;h<NH;++h){ m[h][0]=0.f; m[h][1]=0.f; m[h][2]=0.f; }
  float rs4[4]={0.f,0.f,0.f,0.f}, sa4[4]={0.f,0.f,0.f,0.f}, sb4[4]={0.f,0.f,0.f,0.f};

  const float* hrow = hs + (long)b*SEQ*HDIM;
  const int r32 = t >> 3;               // staging row 0..31
  const int c8  = t & 7;                // 8 threads per row
  const int swzW = (r32 & 7) << 3;      // XOR swizzle (ushort units, 16B granule)

  // stage chunk 0 (rows 0..31 all valid)
  #pragma unroll
  for (int ep=0; ep<12; ++ep) {
    const float* p = hrow + (long)r32*HDIM + (2*c8 + ep*16)*4;
    float4 a  = *(const float4*)p;
    float4 bq = *(const float4*)(p+4);
    uint4 pk; pk.x=cvt2(a.x,a.y); pk.y=cvt2(a.z,a.w); pk.z=cvt2(bq.x,bq.y); pk.w=cvt2(bq.z,bq.w);
    *(uint4*)&xbf[r32*768 + ((8*c8 + ep*64) ^ swzW)] = pk;
  }
  barrier_lds();

  const int sL   = w*8 + (l15 & 7);     // this lane's s-row (l15>=8 duplicates, ignored)
  const int swzR = (l15 & 7) << 3;
  const int hcl  = (l15 < 12) ? l15 : 11;

  float4 g[24];

  for (int c=0; c<NCH; ++c) {
    // ---- score: S^T[h][s] = sum_j u'[h][j] x[s][j], full K per wave ----
    f32x4 acc = {0.f,0.f,0.f,0.f};
    #pragma unroll
    for (int kt=0; kt<24; ++kt) {
      const int off = kt*32 + lg*8;
      uint4 au = *(const uint4*)&uld[hcl*776 + off];
      uint4 bu = *(const uint4*)&xbf[sL*768 + (off ^ swzR)];
      union { uint4 q; short8 s8; } A, B; A.q = au; B.q = bu;
      acc = __builtin_amdgcn_mfma_f32_16x16x32_bf16(A.s8, B.s8, acc, 0, 0, 0);
    }
    // ---- exp per-lane (valid lanes l15<8), write wl row ----
    if (l15 < 8) {
      const int sg = c*CS + w*8 + l15;
      const float al = al_s[sg], be = be_s[sg];
      float4 pb4 = *(const float4*)&pbT[sg*16 + lg*4];
      const float pbv[4] = {pb4.x, pb4.y, pb4.z, pb4.w};
      float wr[4];
      #pragma unroll
      for (int r=0;r<4;++r) {
        int h = lg*4 + r;
        float sc = acc[r] + fmaf(ca4[r], al, fmaf(cb4[r], be, cc4[r])) + pbv[r];
        float wv = (sg < SEQ && h < NH) ? __expf(sc) : 0.f;
        wr[r] = wv;
        rs4[r] += wv;
        sa4[r] = fmaf(wv, al, sa4[r]);
        sb4[r] = fmaf(wv, be, sb4[r]);
      }
      *(float4*)&wl[w*8 + l15][lg*4] = make_float4(wr[0],wr[1],wr[2],wr[3]);
    }
    // ---- issue next-chunk global loads (stay in flight across barriers) ----
    if (c+1 < NCH) {
      int srow = (c+1)*CS + r32; if (srow > SEQ-1) srow = SEQ-1;
      #pragma unroll
      for (int ep=0; ep<12; ++ep) {
        const float* p = hrow + (long)srow*HDIM + (2*c8 + ep*16)*4;
        g[2*ep]   = *(const float4*)p;
        g[2*ep+1] = *(const float4*)(p+4);
      }
    }
    barrier_lds();                       // wl ready
    // ---- PV (VALU): m[h][k] += w[s][h] * x[s][j=t+256k] ----
    #pragma unroll 2
    for (int s=0; s<CS; ++s) {
      const int sw = (s&7) << 3;
      const float* wp = &wl[s][0];
      float4 wa = *(const float4*)wp;
      float4 wb = *(const float4*)(wp+4);
      float4 wc = *(const float4*)(wp+8);
      float x0 = bf_as_f(xbf[s*768 + ( t        ^ sw)]);
      float x1 = bf_as_f(xbf[s*768 + ((t + 256) ^ sw)]);
      float x2 = bf_as_f(xbf[s*768 + ((t + 512) ^ sw)]);
      const float wv12[NH] = {wa.x,wa.y,wa.z,wa.w, wb.x,wb.y,wb.z,wb.w, wc.x,wc.y,wc.z,wc.w};
      #pragma unroll
      for (int h=0; h<NH; ++h) {
        m[h][0] = fmaf(wv12[h], x0, m[h][0]);
        m[h][1] = fmaf(wv12[h], x1, m[h][1]);
        m[h][2] = fmaf(wv12[h], x2, m[h][2]);
      }
    }
    barrier_lds();                       // xbf free
    if (c+1 < NCH) {
      #pragma unroll
      for (int ep=0; ep<12; ++ep) {
        float4 a = g[2*ep], bq = g[2*ep+1];
        uint4 pk; pk.x=cvt2(a.x,a.y); pk.y=cvt2(a.z,a.w); pk.z=cvt2(bq.x,bq.y); pk.w=cvt2(bq.z,bq.w);
        *(uint4*)&xbf[r32*768 + ((8*c8 + ep*64) ^ swzW)] = pk;
      }
      barrier_lds();                     // xbf(c+1) ready
    }
  }

  // ---- reduce softmax partials over s-lanes (lanes l15>=8 hold zeros) ----
  #pragma unroll
  for (int r=0;r<4;++r) {
    #pragma unroll
    for (int mk=1; mk<16; mk<<=1) {
      rs4[r] += __shfl_xor(rs4[r], mk);
      sa4[r] += __shfl_xor(sa4[r], mk);
      sb4[r] += __shfl_xor(sb4[r], mk);
    }
  }
  if (l15 == 0) {
    #pragma unroll
    for (int r=0;r<4;++r) {
      hsum[0][w][lg*4+r] = rs4[r];
      hsum[1][w][lg*4+r] = sa4[r];
      hsum[2][w][lg*4+r] = sb4[r];
    }
  }
  __syncthreads();

  float avv[3], bvv[3], cvv[3];
  #pragma unroll
  for (int k=0;k<3;++k){ avv[k]=Av[t+256*k]; bvv[k]=Bv[t+256*k]; cvv[k]=Cv[t+256*k]; }
  float* mo = mout + (long)bb*(NH*HDIM);
  #pragma unroll
  for (int h=0; h<NH; ++h) {
    float rsum = hsum[0][0][h]+hsum[0][1][h]+hsum[0][2][h]+hsum[0][3][h];
    float sas  = hsum[1][0][h]+hsum[1][1][h]+hsum[1][2][h]+hsum[1][3][h];
    float sbs  = hsum[2][0][h]+hsum[2][1][h]+hsum[2][2][h]+hsum[2][3][h];
    float invr = 1.0f/rsum;
    float fa = sas*invr, fb = sbs*invr;
    #pragma unroll
    for (int k=0;k<3;++k)
      mo[h*HDIM + t + 256*k] = fmaf(m[h][k], invr, fmaf(fa, avv[k], fmaf(fb, bvv[k], cvv[k])));
  }
}

extern "C" void kernel_launch(void* const* d_in, const int* in_sizes, int n_in,
                              void* d_out, int out_size, void* d_ws, size_t ws_size,
                              hipStream_t stream) {
  (void)in_sizes; (void)n_in; (void)out_size;
  const float* hs   = (const float*)d_in[0];
  const float* Wq   = (const float*)d_in[1];
  const float* bq   = (const float*)d_in[2];
  const float* Wk   = (const float*)d_in[3];
  const float* bk   = (const float*)d_in[4];
  const float* Wv   = (const float*)d_in[5];
  const float* bv   = (const float*)d_in[6];
  const float* Wo   = (const float*)d_in[7];
  const float* bo   = (const float*)d_in[8];
  const float* pe_w = (const float*)d_in[9];
  const float* pe_b = (const float*)d_in[10];
  const float* ln_g = (const float*)d_in[11];
  const float* ln_b = (const float*)d_in[12];
  const float* pos_bias = (const float*)d_in[13];
  float* out = (float*)d_out;

  float* wsf   = (float*)d_ws;
  float* pemid = wsf;               // 768
  float* alpha = pemid + 768;       // 288
  float* beta  = alpha + 288;       // 288
  float* Avec  = beta  + 288;       // 768
  float* Bvec  = Avec  + 768;       // 768
  float* Cvec  = Bvec  + 768;       // 768
  float* pbT   = Cvec  + 768;       // 288*16 = 4608
  float* base  = pbT   + 4608;      // fixed total = 8256 floats

  const long perB = 768L + 36L + 9216L + 9216L + 768L;   // q + (ca,cb,cc) + u + m + ctx
  long availF = (long)(ws_size/4) - 8256;
  long chunkB = (availF > 0) ? (availF / perB) : 0;
  if (chunkB > BTOT) chunkB = BTOT;
  chunkB &= ~63L;
  if (chunkB < 64) chunkB = 64;

  float* qb   = base;
  float* cab  = qb  + chunkB*HDIM;
  float* cbb  = cab + chunkB*NH;
  float* ccb  = cbb + chunkB*NH;
  float* ub   = ccb + chunkB*NH;
  float* mb   = ub  + chunkB*(long)NH*HDIM;
  float* ctxb = mb  + chunkB*(long)NH*HDIM;

  k0_pre<<<dim3(1), dim3(256), 0, stream>>>(pe_w, pe_b, ln_g, ln_b, pos_bias,
                                            pemid, alpha, beta, Avec, Bvec, Cvec, pbT);

  for (long b0 = 0; b0 < BTOT; b0 += chunkB) {
    long cbN = (BTOT - b0 < chunkB) ? (BTOT - b0) : chunkB;
    int mt = (int)(cbN/64);
    // K1: q' = 0.125*((hs[:,mid,:] + pe_mid) @ Wq^T + bq)
    gemm64<<<dim3(mt,12,1), dim3(256), 0, stream>>>(
        hs + b0*(long)SEQ*HDIM + (long)MIDP*HDIM, (long)SEQ*HDIM, 0L,
        Wq, (long)HDIM, 0L, 1,
        qb, (long)HDIM, 0L,
        HDIM, bq, 0L, pemid, 0.125f);
    // K2: u'[b,h,:] = q'[b,h,:] @ Wk_h
    gemm64<<<dim3(mt,12,12), dim3(256), 0, stream>>>(
        qb, (long)HDIM, (long)HD,
        Wk, (long)HDIM, (long)HD*HDIM, 0,
        ub, (long)NH*HDIM, (long)HDIM,
        HD, (const float*)nullptr, 0L, (const float*)nullptr, 1.0f);
    // kp: per-(b,h) pe/bias dot scalars
    int nw = (int)(cbN*NH);
    kp<<<dim3((nw+3)/4), dim3(256), 0, stream>>>(qb, ub, bk, Avec, Bvec, Cvec,
                                                 cab, cbb, ccb, (int)cbN);
    // K3: fused MFMA scores + softmax-weighted mean
    k3_mfma<<<dim3((int)cbN), dim3(256), 0, stream>>>(
        hs, (int)b0, ub, cab, cbb, ccb, alpha, beta, Avec, Bvec, Cvec, pbT, mb);
    // K4: ctx = Wv_h @ m + bv
    gemm64<<<dim3(mt,1,12), dim3(256), 0, stream>>>(
        mb, (long)NH*HDIM, (long)HDIM,
        Wv, (long)HDIM, (long)HD*HDIM, 1,
        ctxb, (long)HDIM, (long)HD,
        HDIM, bv, (long)HD, (const float*)nullptr, 1.0f);
    // K5: out = ctx @ Wo^T + bo
    gemm64<<<dim3(mt,12,1), dim3(256), 0, stream>>>(
        ctxb, (long)HDIM, 0L,
        Wo, (long)HDIM, 0L, 1,
        out + b0*(long)HDIM, (long)HDIM, 0L,
        HDIM, bo, 0L, (const float*)nullptr, 1.0f);
  }
}

// Round 8
// 735.955 us; speedup vs baseline: 1.6140x; 1.6140x over previous
//
#include <hip/hip_runtime.h>
#include <hip/hip_bf16.h>
#include <math.h>

#define NH   12
#define HD   64
#define HDIM 768
#define SEQ  257
#define MIDP 128
#define BTOT 2048

typedef __attribute__((ext_vector_type(8))) short short8;
typedef __attribute__((ext_vector_type(4))) float f32x4;

__device__ inline unsigned short f2bf(float x){
  union { float f; unsigned u; } v; v.f = x;
  unsigned r = v.u + 0x7FFFu + ((v.u >> 16) & 1u);
  return (unsigned short)(r >> 16);
}
__device__ inline float bf2f(unsigned short h){
  union { unsigned u; float f; } v; v.u = ((unsigned)h) << 16; return v.f;
}
__device__ inline unsigned cvt2(float lo, float hi){
  union { __hip_bfloat162 h; unsigned u; } z;
  z.h = __float22bfloat162_rn(make_float2(lo, hi));   // lo -> low 16 bits
  return z.u;
}
__device__ inline float dot4(float4 a, float4 b){
  return fmaf(a.x,b.x, fmaf(a.y,b.y, fmaf(a.z,b.z, a.w*b.w)));
}
// LDS-only barrier: drain LDS ops, leave global loads in flight
__device__ inline void barrier_lds(){
  __builtin_amdgcn_sched_barrier(0);
  asm volatile("s_waitcnt lgkmcnt(0)" ::: "memory");
  __builtin_amdgcn_s_barrier();
  __builtin_amdgcn_sched_barrier(0);
}

// ---------------- K0: moments + pe rank-3 decomposition tables ----------------
__global__ __launch_bounds__(256) void k0_pre(
    const float* __restrict__ pe_w, const float* __restrict__ pe_b,
    const float* __restrict__ ln_g, const float* __restrict__ ln_b,
    const float* __restrict__ pos_bias,
    float* __restrict__ pemid, float* __restrict__ alpha, float* __restrict__ beta,
    float* __restrict__ Av, float* __restrict__ Bv, float* __restrict__ Cv,
    float* __restrict__ pbT) {
  __shared__ float red[5][256];
  const int t = threadIdx.x;
  float sw=0.f, sb=0.f, sww=0.f, swb=0.f, sbb=0.f;
  for (int j=t; j<HDIM; j+=256) {
    float w=pe_w[j], b=pe_b[j];
    sw+=w; sb+=b; sww+=w*w; swb+=w*b; sbb+=b*b;
  }
  red[0][t]=sw; red[1][t]=sb; red[2][t]=sww; red[3][t]=swb; red[4][t]=sbb;
  __syncthreads();
  for (int off=128; off>0; off>>=1) {
    if (t<off) {
      red[0][t]+=red[0][t+off]; red[1][t]+=red[1][t+off]; red[2][t]+=red[2][t+off];
      red[3][t]+=red[3][t+off]; red[4][t]+=red[4][t+off];
    }
    __syncthreads();
  }
  const float inv = 1.0f/(float)HDIM;
  const float mw=red[0][0]*inv, mc=red[1][0]*inv;
  const float Vw =red[2][0]*inv - mw*mw;
  const float Cwc=red[3][0]*inv - mw*mc;
  const float Vc =red[4][0]*inv - mc*mc;
  for (int s=t; s<288; s+=256) {
    if (s < SEQ) {
      float pos = (float)(s - MIDP) / ((float)MIDP + 1e-6f);
      float var = pos*pos*Vw + 2.f*pos*Cwc + Vc;
      float rstd = rsqrtf(var + 1e-5f);
      alpha[s] = pos*rstd; beta[s] = rstd;
    } else { alpha[s] = 0.f; beta[s] = 0.f; }
  }
  const float rstd0 = rsqrtf(Vc + 1e-5f);
  for (int j=t; j<HDIM; j+=256) {
    float g = ln_g[j];
    Av[j] = (pe_w[j]-mw)*g;
    Bv[j] = (pe_b[j]-mc)*g;
    Cv[j] = ln_b[j];
    pemid[j] = (pe_b[j]-mc)*rstd0*g + ln_b[j];
  }
  for (int i=t; i<288*16; i+=256) {
    int s = i>>4, h = i&15;
    pbT[i] = (s<SEQ && h<NH) ? pos_bias[h*SEQ+s] : 0.f;
  }
}

// ---------------- tiled fp32 GEMM with epilogue scale ----------------
__global__ __launch_bounds__(256) void gemm64(
    const float* __restrict__ A, long lda, long aoffz,
    const float* __restrict__ Bm, long ldb, long boffz, int bT,
    float* __restrict__ C, long ldc, long coffz,
    int K,
    const float* __restrict__ bias, long biasoffz,
    const float* __restrict__ avec, float scale) {
  __shared__ __align__(16) float As[16][68];
  __shared__ __align__(16) float Bs[16][68];
  const int tid = threadIdx.x;
  const int tx = tid & 15, ty = tid >> 4;
  const int z = blockIdx.z;
  const long n0 = (long)blockIdx.y * 64;
  A  += (long)blockIdx.x*64*lda + (long)z*aoffz;
  Bm += (long)z*boffz;
  C  += (long)blockIdx.x*64*ldc + n0 + (long)z*coffz;
  float acc[4][4] = {};
  const int lm = tid & 63;
  const int lk = tid >> 6;

  for (int k0 = 0; k0 < K; k0 += 16) {
    float4 a = *(const float4*)&A[(long)lm*lda + k0 + lk*4];
    if (avec) {
      float4 av = *(const float4*)&avec[k0 + lk*4];
      a.x += av.x; a.y += av.y; a.z += av.z; a.w += av.w;
    }
    As[lk*4+0][lm]=a.x; As[lk*4+1][lm]=a.y; As[lk*4+2][lm]=a.z; As[lk*4+3][lm]=a.w;
    if (bT) {
      float4 b = *(const float4*)&Bm[(n0+lm)*ldb + k0 + lk*4];
      Bs[lk*4+0][lm]=b.x; Bs[lk*4+1][lm]=b.y; Bs[lk*4+2][lm]=b.z; Bs[lk*4+3][lm]=b.w;
    } else {
      #pragma unroll
      for (int i=0;i<4;i++)
        Bs[lk*4+i][lm] = Bm[(long)(k0+lk*4+i)*ldb + n0 + lm];
    }
    __syncthreads();
    #pragma unroll
    for (int k=0;k<16;k++) {
      float4 a4 = *(const float4*)&As[k][ty*4];
      float4 b4 = *(const float4*)&Bs[k][tx*4];
      float aa[4] = {a4.x,a4.y,a4.z,a4.w};
      float bb[4] = {b4.x,b4.y,b4.z,b4.w};
      #pragma unroll
      for (int i=0;i<4;i++)
        #pragma unroll
        for (int j=0;j<4;j++)
          acc[i][j] = fmaf(aa[i], bb[j], acc[i][j]);
    }
    __syncthreads();
  }
  float4 bs = make_float4(0.f,0.f,0.f,0.f);
  if (bias) bs = *(const float4*)&bias[(long)z*biasoffz + n0 + tx*4];
  #pragma unroll
  for (int i=0;i<4;i++) {
    float4 o;
    o.x = (acc[i][0]+bs.x)*scale; o.y = (acc[i][1]+bs.y)*scale;
    o.z = (acc[i][2]+bs.z)*scale; o.w = (acc[i][3]+bs.w)*scale;
    *(float4*)&C[(long)(ty*4+i)*ldc + tx*4] = o;
  }
}

// ---------------- kp: per-(b,h) scalars ca=u'.A, cb=u'.B, cc=u'.C + q'.bk ----------------
__global__ __launch_bounds__(256) void kp(
    const float* __restrict__ q, const float* __restrict__ u, const float* __restrict__ bk,
    const float* __restrict__ Av, const float* __restrict__ Bv, const float* __restrict__ Cv,
    float* __restrict__ ca, float* __restrict__ cb, float* __restrict__ cc, int nb) {
  const int wid = blockIdx.x*4 + (threadIdx.x >> 6);
  const int lane = threadIdx.x & 63;
  if (wid >= nb*NH) return;
  const int b = wid / NH, h = wid % NH;
  const float* up = u + (long)b*(NH*HDIM) + h*HDIM;
  float pa=0.f, pb_=0.f, pc=0.f;
  #pragma unroll
  for (int e=0;e<3;e++) {
    int c4 = (lane + 64*e)*4;
    float4 uu = *(const float4*)&up[c4];
    pa += dot4(uu, *(const float4*)&Av[c4]);
    pb_+= dot4(uu, *(const float4*)&Bv[c4]);
    pc += dot4(uu, *(const float4*)&Cv[c4]);
  }
  if (lane < 16) {
    float4 qq = *(const float4*)&q[(long)b*HDIM + h*HD + lane*4];
    float4 bb = *(const float4*)&bk[h*HD + lane*4];
    pc += dot4(qq, bb);
  }
  #pragma unroll
  for (int mlog=0; mlog<6; mlog++) {
    int msk = 1<<mlog;
    pa += __shfl_xor(pa, msk);
    pb_+= __shfl_xor(pb_, msk);
    pc += __shfl_xor(pc, msk);
  }
  if (lane == 0) { ca[wid]=pa; cb[wid]=pb_; cc[wid]=pc; }
}

// ---------------- K3 v8: dual-layout LDS (x_row + colT), all-MFMA score & PV ----------------
// Block per batch, CS=16 chunks. Stager: 2 rows x 24 interleaved cols/thread;
// writes x_row (b64, XOR swizzle (s&7)<<3) and colT[j][s] (s-pairs packed b32,
// XOR ((j>>2)&1)<<3). Score: round-3 K-split MFMA (A=x_row rows, B=uf regs) + sred.
// Exp: wave 0 only -> wlT[h][s] bf16. PV: mfma(A=colT rows (lane=j), B=wlT row
// (lane=h)) -> m^T in regs. 3 lgkm-only barriers/chunk; vmcnt never drained.
__global__ __launch_bounds__(256, 2) void k3_v8(
    const float* __restrict__ hs, int b0,
    const float* __restrict__ u,
    const float* __restrict__ ca, const float* __restrict__ cb, const float* __restrict__ cc,
    const float* __restrict__ alpha, const float* __restrict__ beta,
    const float* __restrict__ Av, const float* __restrict__ Bv, const float* __restrict__ Cv,
    const float* __restrict__ pbT, float* __restrict__ mout) {
  const int t   = threadIdx.x;
  const int l   = t & 63;
  const int w   = t >> 6;
  const int l15 = l & 15;
  const int lg  = l >> 4;
  const int bb  = blockIdx.x;
  const int b   = b0 + bb;

  __shared__ __align__(16) unsigned short xbuf[2*12288];  // x_row[16*768] | colT[768*16]
  unsigned short* xrow = xbuf;
  unsigned short* colT = xbuf + 12288;
  __shared__ float sred[4][16][17];                       // 4.4 KB
  __shared__ __align__(16) unsigned short wlT[16*16];     // [h][s] bf16, 512 B
  __shared__ float hsum[3][16];

  // u' B-frags (score), wave w covers K-quarter [w*192, +192)
  const float* ub = u + (long)bb*(NH*HDIM);
  short8 uf[6];
  #pragma unroll
  for (int kt=0; kt<6; kt++) {
    union { uint4 q; short8 s8; } s; s.q = make_uint4(0,0,0,0);
    if (l15 < NH) {
      const float* p = ub + l15*HDIM + w*192 + kt*32 + lg*8;
      float4 x0 = *(const float4*)p;
      float4 x1 = *(const float4*)(p+4);
      s.q.x = cvt2(x0.x,x0.y); s.q.y = cvt2(x0.z,x0.w);
      s.q.z = cvt2(x1.x,x1.y); s.q.w = cvt2(x1.z,x1.w);
    }
    uf[kt] = s.s8;
  }
  float cah=0.f, cbh=0.f, cch=0.f;
  if (w==0 && l15<NH) { cah=ca[bb*NH+l15]; cbh=cb[bb*NH+l15]; cch=cc[bb*NH+l15]; }

  f32x4 pv[12];
  #pragma unroll
  for (int i=0;i<12;i++){ f32x4 z={0.f,0.f,0.f,0.f}; pv[i]=z; }
  float rs_p=0.f, sa_p=0.f, sb_p=0.f;

  const float* hrow = hs + (long)b*SEQ*HDIM;
  const int rp = t >> 5;          // 0..7: rows rp*2, rp*2+1
  const int cq = t & 31;          // interleaved col-quads: j = cq*4 + e*128 + d
  union { float4 v4[12]; float f[48]; } g;   // [rr*6+e]

  // chunk-0 load + stage
  #pragma unroll
  for (int rr=0; rr<2; ++rr)
    #pragma unroll
    for (int e=0; e<6; ++e)
      g.v4[rr*6+e] = *(const float4*)&hrow[(long)(rp*2+rr)*HDIM + cq*4 + e*128];
  #pragma unroll
  for (int rr=0; rr<2; ++rr) {
    const int srow = rp*2+rr;
    #pragma unroll
    for (int e=0; e<6; ++e) {
      float4 v = g.v4[rr*6+e];
      uint2 pk; pk.x = cvt2(v.x,v.y); pk.y = cvt2(v.z,v.w);
      const int c = cq*4 + e*128;
      *(uint2*)&xrow[srow*768 + (c ^ ((srow&7)<<3))] = pk;
    }
  }
  #pragma unroll
  for (int e=0; e<6; ++e)
    #pragma unroll
    for (int d=0; d<4; ++d) {
      const int j = cq*4 + e*128 + d;
      unsigned v = cvt2(g.f[e*4+d], g.f[24+e*4+d]);
      *(unsigned*)&colT[j*16 + ((rp*2) ^ (((j>>2)&1)<<3))] = v;
    }
  __syncthreads();

  #pragma unroll 1
  for (int c=0; c<17; ++c) {
    // issue next-chunk loads (ride across lgkm barriers)
    if (c < 16) {
      #pragma unroll
      for (int rr=0; rr<2; ++rr) {
        int sg = (c+1)*16 + rp*2 + rr; if (sg > SEQ-1) sg = SEQ-1;
        #pragma unroll
        for (int e=0; e<6; ++e)
          g.v4[rr*6+e] = *(const float4*)&hrow[(long)sg*HDIM + cq*4 + e*128];
      }
    }
    // ---- score MFMA (K-quarter per wave) ----
    {
      f32x4 acc = {0.f,0.f,0.f,0.f};
      #pragma unroll
      for (int kt=0; kt<6; kt++) {
        const int col = w*192 + kt*32 + lg*8;
        uint4 raw = *(const uint4*)&xrow[l15*768 + (col ^ ((l15&7)<<3))];
        union { uint4 q; short8 s8; } A; A.q = raw;
        acc = __builtin_amdgcn_mfma_f32_16x16x32_bf16(A.s8, uf[kt], acc, 0, 0, 0);
      }
      #pragma unroll
      for (int r=0; r<4; ++r) sred[w][lg*4+r][l15] = acc[r];
    }
    barrier_lds();                        // BAR1: sred ready
    // ---- exp on wave 0 only -> wlT ----
    if (w == 0) {
      #pragma unroll
      for (int r=0; r<4; ++r) {
        const int s = lg*4 + r, sg = c*16 + s;
        float S = sred[0][s][l15]+sred[1][s][l15]+sred[2][s][l15]+sred[3][s][l15];
        float al = alpha[sg], be = beta[sg];
        float sc = S + fmaf(cah, al, fmaf(cbh, be, cch)) + pbT[sg*16 + l15];
        float wv = (sg < SEQ && l15 < NH) ? __expf(sc) : 0.f;
        unsigned short wb = f2bf(wv);
        float wr = bf2f(wb);
        rs_p += wr; sa_p = fmaf(wr, al, sa_p); sb_p = fmaf(wr, be, sb_p);
        wlT[l15*16 + s] = wb;
      }
    }
    barrier_lds();                        // BAR2: wlT ready
    // ---- PV MFMA: m^T[j][h] += x^T * w ----
    {
      union { uint4 q; short8 s8; } B; B.q = make_uint4(0,0,0,0);
      if (lg < 2) B.q = *(const uint4*)&wlT[l15*16 + lg*8];
      #pragma unroll
      for (int tau=0; tau<12; ++tau) {
        const int j = w*192 + tau*16 + l15;
        union { uint4 q; short8 s8; } A; A.q = make_uint4(0,0,0,0);
        if (lg < 2) A.q = *(const uint4*)&colT[j*16 + ((lg*8) ^ (((j>>2)&1)<<3))];
        pv[tau] = __builtin_amdgcn_mfma_f32_16x16x32_bf16(A.s8, B.s8, pv[tau], 0, 0, 0);
      }
      // stage next x_row (score(c) done reading since BAR1)
      if (c < 16) {
        #pragma unroll
        for (int rr=0; rr<2; ++rr) {
          const int srow = rp*2+rr;
          #pragma unroll
          for (int e=0; e<6; ++e) {
            float4 v = g.v4[rr*6+e];
            uint2 pk; pk.x = cvt2(v.x,v.y); pk.y = cvt2(v.z,v.w);
            const int cc2 = cq*4 + e*128;
            *(uint2*)&xrow[srow*768 + (cc2 ^ ((srow&7)<<3))] = pk;
          }
        }
      }
    }
    barrier_lds();                        // BAR3: PV done -> colT writable
    if (c < 16) {
      #pragma unroll
      for (int e=0; e<6; ++e)
        #pragma unroll
        for (int d=0; d<4; ++d) {
          const int j = cq*4 + e*128 + d;
          unsigned v = cvt2(g.f[e*4+d], g.f[24+e*4+d]);
          *(unsigned*)&colT[j*16 + ((rp*2) ^ (((j>>2)&1)<<3))] = v;
        }
    }
    // colT writes drain at next BAR1 (before any PV(c+1) read) — safe.
  }

  // ---- softmax sums (wave 0 holds partials over s = lg*4+r) ----
  if (w == 0) {
    rs_p += __shfl_xor(rs_p,16); rs_p += __shfl_xor(rs_p,32);
    sa_p += __shfl_xor(sa_p,16); sa_p += __shfl_xor(sa_p,32);
    sb_p += __shfl_xor(sb_p,16); sb_p += __shfl_xor(sb_p,32);
    if (l < 16) { hsum[0][l15]=rs_p; hsum[1][l15]=sa_p; hsum[2][l15]=sb_p; }
  }
  __syncthreads();

  // ---- m^T regs -> LDS (overlay xbuf), then coalesced epilogue ----
  float* mlds = (float*)xbuf;             // [12][772]
  if (l15 < NH) {
    #pragma unroll
    for (int tau=0; tau<12; ++tau)
      #pragma unroll
      for (int r=0; r<4; ++r) {
        const int j = w*192 + tau*16 + lg*4 + r;
        mlds[l15*772 + j] = pv[tau][r];
      }
  }
  __syncthreads();
  float* mo = mout + (long)bb*(NH*HDIM);
  #pragma unroll
  for (int e=0; e<9; ++e) {
    const int idx = t + 256*e;            // 0..2303
    const int h = idx/192, c4 = (idx%192)*4;
    const float invr = 1.0f/hsum[0][h];
    const float fa = hsum[1][h]*invr, fb = hsum[2][h]*invr;
    float4 mv = *(const float4*)&mlds[h*772 + c4];
    float4 av = *(const float4*)&Av[c4];
    float4 bv4 = *(const float4*)&Bv[c4];
    float4 cv4 = *(const float4*)&Cv[c4];
    float4 o;
    o.x = fmaf(mv.x, invr, fmaf(fa, av.x, fmaf(fb, bv4.x, cv4.x)));
    o.y = fmaf(mv.y, invr, fmaf(fa, av.y, fmaf(fb, bv4.y, cv4.y)));
    o.z = fmaf(mv.z, invr, fmaf(fa, av.z, fmaf(fb, bv4.z, cv4.z)));
    o.w = fmaf(mv.w, invr, fmaf(fa, av.w, fmaf(fb, bv4.w, cv4.w)));
    *(float4*)&mo[h*HDIM + c4] = o;
  }
}

extern "C" void kernel_launch(void* const* d_in, const int* in_sizes, int n_in,
                              void* d_out, int out_size, void* d_ws, size_t ws_size,
                              hipStream_t stream) {
  (void)in_sizes; (void)n_in; (void)out_size;
  const float* hs   = (const float*)d_in[0];
  const float* Wq   = (const float*)d_in[1];
  const float* bq   = (const float*)d_in[2];
  const float* Wk   = (const float*)d_in[3];
  const float* bk   = (const float*)d_in[4];
  const float* Wv   = (const float*)d_in[5];
  const float* bv   = (const float*)d_in[6];
  const float* Wo   = (const float*)d_in[7];
  const float* bo   = (const float*)d_in[8];
  const float* pe_w = (const float*)d_in[9];
  const float* pe_b = (const float*)d_in[10];
  const float* ln_g = (const float*)d_in[11];
  const float* ln_b = (const float*)d_in[12];
  const float* pos_bias = (const float*)d_in[13];
  float* out = (float*)d_out;

  float* wsf   = (float*)d_ws;
  float* pemid = wsf;               // 768
  float* alpha = pemid + 768;       // 288
  float* beta  = alpha + 288;       // 288
  float* Avec  = beta  + 288;       // 768
  float* Bvec  = Avec  + 768;       // 768
  float* Cvec  = Bvec  + 768;       // 768
  float* pbT   = Cvec  + 768;       // 288*16 = 4608
  float* base  = pbT   + 4608;      // fixed total = 8256 floats

  const long perB = 768L + 36L + 9216L + 9216L + 768L;   // q + (ca,cb,cc) + u + m + ctx
  long availF = (long)(ws_size/4) - 8256;
  long chunkB = (availF > 0) ? (availF / perB) : 0;
  if (chunkB > BTOT) chunkB = BTOT;
  chunkB &= ~63L;
  if (chunkB < 64) chunkB = 64;

  float* qb   = base;
  float* cab  = qb  + chunkB*HDIM;
  float* cbb  = cab + chunkB*NH;
  float* ccb  = cbb + chunkB*NH;
  float* ub   = ccb + chunkB*NH;
  float* mb   = ub  + chunkB*(long)NH*HDIM;
  float* ctxb = mb  + chunkB*(long)NH*HDIM;

  k0_pre<<<dim3(1), dim3(256), 0, stream>>>(pe_w, pe_b, ln_g, ln_b, pos_bias,
                                            pemid, alpha, beta, Avec, Bvec, Cvec, pbT);

  for (long b0 = 0; b0 < BTOT; b0 += chunkB) {
    long cbN = (BTOT - b0 < chunkB) ? (BTOT - b0) : chunkB;
    int mt = (int)(cbN/64);
    // K1: q' = 0.125*((hs[:,mid,:] + pe_mid) @ Wq^T + bq)
    gemm64<<<dim3(mt,12,1), dim3(256), 0, stream>>>(
        hs + b0*(long)SEQ*HDIM + (long)MIDP*HDIM, (long)SEQ*HDIM, 0L,
        Wq, (long)HDIM, 0L, 1,
        qb, (long)HDIM, 0L,
        HDIM, bq, 0L, pemid, 0.125f);
    // K2: u'[b,h,:] = q'[b,h,:] @ Wk_h
    gemm64<<<dim3(mt,12,12), dim3(256), 0, stream>>>(
        qb, (long)HDIM, (long)HD,
        Wk, (long)HDIM, (long)HD*HDIM, 0,
        ub, (long)NH*HDIM, (long)HDIM,
        HD, (const float*)nullptr, 0L, (const float*)nullptr, 1.0f);
    // kp: per-(b,h) pe/bias dot scalars
    int nw = (int)(cbN*NH);
    kp<<<dim3((nw+3)/4), dim3(256), 0, stream>>>(qb, ub, bk, Avec, Bvec, Cvec,
                                                 cab, cbb, ccb, (int)cbN);
    // K3: fused MFMA scores + softmax-weighted mean
    k3_v8<<<dim3((int)cbN), dim3(256), 0, stream>>>(
        hs, (int)b0, ub, cab, cbb, ccb, alpha, beta, Avec, Bvec, Cvec, pbT, mb);
    // K4: ctx = Wv_h @ m + bv
    gemm64<<<dim3(mt,1,12), dim3(256), 0, stream>>>(
        mb, (long)NH*HDIM, (long)HDIM,
        Wv, (long)HDIM, (long)HD*HDIM, 1,
        ctxb, (long)HDIM, (long)HD,
        HDIM, bv, (long)HD, (const float*)nullptr, 1.0f);
    // K5: out = ctx @ Wo^T + bo
    gemm64<<<dim3(mt,12,1), dim3(256), 0, stream>>>(
        ctxb, (long)HDIM, 0L,
        Wo, (long)HDIM, 0L, 1,
        out + b0*(long)HDIM, (long)HDIM, 0L,
        HDIM, bo, 0L, (const float*)nullptr, 1.0f);
  }
}